// Round 3
// baseline (318.919 us; speedup 1.0000x reference)
//
#include <hip/hip_runtime.h>

typedef float v2f __attribute__((ext_vector_type(2)));

#define HID 10
#define NIN 6
#define SEQT 512
#define TC 16
#define NCHUNK (SEQT/TC)
#define BPB 32            // batches per block (8 lanes per batch * 32 = 256 threads)
#define NTHR 256
#define XSTRIDE 100       // floats per batch row in LDS (96 + 4 pad -> conflict-free reads)

// broadcast lane L (0..3) of each quad via DPP quad_perm (full-rate VALU)
#define QB(v, L) __int_as_float(__builtin_amdgcn_mov_dpp(__float_as_int(v), (L)*0x55, 0xf, 0xf, true))
// exchange lane l <-> 7-l within each 8-lane group (row_half_mirror)
#define HMIR(v)  __int_as_float(__builtin_amdgcn_mov_dpp(__float_as_int(v), 0x141, 0xf, 0xf, true))

__device__ __forceinline__ float fast_exp2(float x){ float r; asm("v_exp_f32 %0, %1" : "=v"(r) : "v"(x)); return r; }
__device__ __forceinline__ float fast_rcp (float x){ float r; asm("v_rcp_f32 %0, %1" : "=v"(r) : "v"(x)); return r; }

// 8 lanes per batch: typ = lane&3 (i,f,g,o), hf = (lane>>2)&1 (u-parity).
// Each lane: 5 gate pre-activations (its typ, parity's u's). Quad shares gates
// via quad_perm DPP; halves exchange h via row_half_mirror.
// amdgpu_waves_per_eu(2,2): grid supplies exactly 2 waves/SIMD, so pin the
// register budget there (256 VGPR) — stops the allocator from spilling the
// weight arrays to chase 6-wave occupancy we can never use (R2: VGPR=80 +
// 28 MB scratch writes).
__global__ __launch_bounds__(NTHR)
__attribute__((amdgpu_waves_per_eu(2, 2)))
void Model_88459146428723_kernel(const float* __restrict__ x,
                                 const float* __restrict__ Wih,
                                 const float* __restrict__ Whh,
                                 const float* __restrict__ bih,
                                 const float* __restrict__ bhh,
                                 const float* __restrict__ Wfc,
                                 const float* __restrict__ bfc,
                                 float* __restrict__ out)
{
    __shared__ float xs[2][BPB*XSTRIDE + 8];   // +8: prefetch overshoot pad
    const int tid = threadIdx.x;
    const int l8  = tid & 7;
    const int typ = tid & 3;
    const int hf  = (tid >> 2) & 1;
    const int bl  = tid >> 3;              // local batch 0..31

    // ---- preload weights: 5 rows (typ, u = 2*uu+hf) ----
    v2f   wih[5][3];
    v2f   whh[5][5];
    v2f   biasv[5];                        // {b, 0} accumulator seed
    #pragma unroll
    for (int uu=0; uu<5; ++uu){
        const int row = typ*HID + 2*uu + hf;
        const float* wi = Wih + (size_t)row*NIN;
        #pragma unroll
        for (int k=0; k<3; ++k){ v2f t = {wi[2*k], wi[2*k+1]}; wih[uu][k] = t; }
        const float* wh = Whh + (size_t)row*HID;
        #pragma unroll
        for (int k=0; k<5; ++k){ v2f t = {wh[2*k + hf], wh[2*k + 1 - hf]}; whh[uu][k] = t; }
        v2f bv = {bih[row] + bhh[row], 0.f};
        biasv[uu] = bv;
    }
    // branch-free activation constants: sigmoid for i,f,o; tanh = 2*sigmoid(2x)-1 for g
    const float expk = (typ==2) ? -2.8853900817779268f : -1.4426950408889634f;
    const float pm   = (typ==2) ?  2.0f : 1.0f;
    const float pa   = (typ==2) ? -1.0f : 0.0f;

    const float* xrow = x + (size_t)blockIdx.x * BPB * (SEQT*NIN);
    float4 stage[3];

    auto load_chunk = [&](int cidx){
        #pragma unroll
        for (int k=0; k<3; ++k){
            int f = tid + k*NTHR;          // float4 index in [0,768)
            int r = f/24, col = f - r*24;  // 24 float4 per batch-row per chunk
            stage[k] = *reinterpret_cast<const float4*>(
                xrow + (size_t)r*(SEQT*NIN) + cidx*(TC*NIN) + col*4);
        }
    };
    auto write_chunk = [&](int buf){
        #pragma unroll
        for (int k=0; k<3; ++k){
            int f = tid + k*NTHR;
            int r = f/24, col = f - r*24;
            *reinterpret_cast<float4*>(&xs[buf][r*XSTRIDE + col*4]) = stage[k];
        }
    };

    load_chunk(0); write_chunk(0); __syncthreads();

    v2f   hp[5];     // h pairs: hp[k] = (h[2k+hf], h[2k+1-hf]) — replicated in 8-group
    float cst[5];    // c for my parity's u's (replicated within quad)
    #pragma unroll
    for (int k=0; k<5; ++k){ v2f z = {0.f,0.f}; hp[k] = z; cst[k] = 0.f; }

    // one LSTM step given this step's x pairs
    auto lstm_step = [&](const v2f* xp){
        float s[5];
        #pragma unroll
        for (int uu=0; uu<5; ++uu){
            v2f acc = biasv[uu];
            #pragma unroll
            for (int k=0; k<3; ++k) acc = __builtin_elementwise_fma(xp[k], wih[uu][k], acc);
            #pragma unroll
            for (int k=0; k<5; ++k) acc = __builtin_elementwise_fma(hp[k], whh[uu][k], acc);
            s[uu] = acc.x + acc.y;
        }
        float act[5];
        #pragma unroll
        for (int uu=0; uu<5; ++uu){
            float e = fast_exp2(s[uu]*expk);
            act[uu] = fmaf(pm, fast_rcp(1.0f + e), pa);
        }
        #pragma unroll
        for (int uu=0; uu<5; ++uu){
            float ia = QB(act[uu], 0);
            float fa = QB(act[uu], 1);
            float ga = QB(act[uu], 2);
            float oa = QB(act[uu], 3);
            float cu = fmaf(fa, cst[uu], ia*ga);
            cst[uu] = cu;
            float e  = fast_exp2(cu * -2.8853900817779268f);
            float th = fmaf(2.0f, fast_rcp(1.0f + e), -1.0f);   // tanh(cu)
            float hmy = oa * th;                                // h[2uu+hf]
            float hot = HMIR(hmy);                              // h[2uu+1-hf]
            v2f hv = {hmy, hot};
            hp[uu] = hv;
        }
    };

    for (int ch=0; ch<NCHUNK; ++ch){
        const float* xb = &xs[ch&1][bl*XSTRIDE];
        if (ch+1 < NCHUNK) load_chunk(ch+1);     // global -> regs, consumed 16 steps later

        v2f xa[3], xq[3];
        #pragma unroll
        for (int k=0; k<3; ++k) xa[k] = *reinterpret_cast<const v2f*>(xb + 2*k);

        // 2-unrolled: alternating register sets, LDS read issued one step ahead
        for (int tt=0; tt<TC; tt+=2){
            #pragma unroll
            for (int k=0; k<3; ++k) xq[k] = *reinterpret_cast<const v2f*>(xb + (tt+1)*NIN + 2*k);
            lstm_step(xa);
            #pragma unroll
            for (int k=0; k<3; ++k) xa[k] = *reinterpret_cast<const v2f*>(xb + (tt+2)*NIN + 2*k); // overshoot at wrap hits pad, unused
            lstm_step(xq);
        }
        if (ch+1 < NCHUNK) write_chunk((ch+1)&1);
        __syncthreads();
    }

    // final FC + sigmoid: lanes l8==0,1 (half 0 -> natural pair order) write the 2 outputs
    if (l8 < 2){
        float a = bfc[l8];
        const float* wf = Wfc + l8*HID;
        #pragma unroll
        for (int k=0; k<5; ++k){
            a = fmaf(hp[k].x, wf[2*k],   a);
            a = fmaf(hp[k].y, wf[2*k+1], a);
        }
        float e = fast_exp2(a * -1.4426950408889634f);
        const int b = blockIdx.x*BPB + bl;
        out[(size_t)b*2 + l8] = fast_rcp(1.0f + e);
    }
}

extern "C" void kernel_launch(void* const* d_in, const int* in_sizes, int n_in,
                              void* d_out, int out_size, void* d_ws, size_t ws_size,
                              hipStream_t stream) {
    const float* x   = (const float*)d_in[0];
    const float* Wih = (const float*)d_in[1];
    const float* Whh = (const float*)d_in[2];
    const float* bih = (const float*)d_in[3];
    const float* bhh = (const float*)d_in[4];
    const float* Wfc = (const float*)d_in[5];
    const float* bfc = (const float*)d_in[6];
    float* out = (float*)d_out;

    dim3 grid(16384 / BPB);   // 512 blocks -> 2 per CU -> 2 waves/SIMD
    dim3 block(NTHR);
    Model_88459146428723_kernel<<<grid, block, 0, stream>>>(x, Wih, Whh, bih, bhh, Wfc, bfc, out);
}

// Round 5
// 298.171 us; speedup vs baseline: 1.0696x; 1.0696x over previous
//
#include <hip/hip_runtime.h>

typedef float v2f __attribute__((ext_vector_type(2)));

#define HID 10
#define NIN 6
#define SEQT 512
#define TC 16
#define NCHUNK (SEQT/TC)
#define BPB 32            // batches per block (8 lanes per batch * 32 = 256 threads)
#define NTHR 256
#define XSTRIDE 100       // floats per batch row in LDS (96 + 4 pad)

// broadcast lane L (0..3) of each quad via DPP quad_perm (full-rate VALU)
#define QB(v, L) __int_as_float(__builtin_amdgcn_mov_dpp(__float_as_int(v), (L)*0x55, 0xf, 0xf, true))
// exchange lane l <-> 7-l within each 8-lane group (row_half_mirror)
#define HMIR(v)  __int_as_float(__builtin_amdgcn_mov_dpp(__float_as_int(v), 0x141, 0xf, 0xf, true))

__device__ __forceinline__ float fast_exp2(float x){ float r; asm("v_exp_f32 %0, %1" : "=v"(r) : "v"(x)); return r; }
__device__ __forceinline__ float fast_rcp (float x){ float r; asm("v_rcp_f32 %0, %1" : "=v"(r) : "v"(x)); return r; }
// packed 2xf32 FMA — force v_pk_fma_f32 (the compiler scalarizes elementwise fma on v2f)
__device__ __forceinline__ v2f pk_fma(v2f a, v2f b, v2f c){
    v2f d; asm("v_pk_fma_f32 %0, %1, %2, %3" : "=v"(d) : "v"(a), "v"(b), "v"(c)); return d;
}

// 8 lanes per batch: typ = lane&3 (i,f,g,o), hf = (lane>>2)&1 (u-parity).
// Each lane: 5 gate pre-activations (its typ, parity's u's). Quad shares gates
// via quad_perm DPP; tanh(c) split across the quad (lane typ owns uu=typ, all
// own uu=4) and re-shared with 4 DPP; halves exchange h via row_half_mirror.
__global__ __launch_bounds__(NTHR)
__attribute__((amdgpu_waves_per_eu(2, 2)))
void Model_88459146428723_kernel(const float* __restrict__ x,
                                 const float* __restrict__ Wih,
                                 const float* __restrict__ Whh,
                                 const float* __restrict__ bih,
                                 const float* __restrict__ bhh,
                                 const float* __restrict__ Wfc,
                                 const float* __restrict__ bfc,
                                 float* __restrict__ out)
{
    __shared__ float xs[2][BPB*XSTRIDE + 8];   // +8: prefetch overshoot pad
    const int tid = threadIdx.x;
    const int l8  = tid & 7;
    const int typ = tid & 3;
    const int hf  = (tid >> 2) & 1;
    const int bl  = tid >> 3;              // local batch 0..31
    const bool tb0 = (typ & 1) != 0;
    const bool tb1 = (typ & 2) != 0;

    // ---- preload weights: 5 rows (typ, u = 2*uu+hf) ----
    v2f wih[5][3];
    v2f whh[5][5];
    v2f biasv[5];                          // {b, 0} accumulator seed
    #pragma unroll
    for (int uu=0; uu<5; ++uu){
        const int row = typ*HID + 2*uu + hf;
        const float* wi = Wih + (size_t)row*NIN;
        #pragma unroll
        for (int k=0; k<3; ++k){ v2f t = {wi[2*k], wi[2*k+1]}; wih[uu][k] = t; }
        const float* wh = Whh + (size_t)row*HID;
        #pragma unroll
        for (int k=0; k<5; ++k){ v2f t = {wh[2*k + hf], wh[2*k + 1 - hf]}; whh[uu][k] = t; }
        v2f bv = {bih[row] + bhh[row], 0.f};
        biasv[uu] = bv;
    }
    // branch-free activation constants: sigmoid for i,f,o; tanh = 2*sigmoid(2x)-1 for g
    const float expk = (typ==2) ? -2.8853900817779268f : -1.4426950408889634f;
    const float pm   = (typ==2) ?  2.0f : 1.0f;
    const float pa   = (typ==2) ? -1.0f : 0.0f;

    const float* xrow = x + (size_t)blockIdx.x * BPB * (SEQT*NIN);
    float4 stg[3];

    // prologue: stage chunk 0
    #pragma unroll
    for (int k=0; k<3; ++k){
        int f = tid + k*NTHR; int r = f/24, c = f - r*24;
        stg[k] = *reinterpret_cast<const float4*>(xrow + (size_t)r*(SEQT*NIN) + c*4);
    }
    #pragma unroll
    for (int k=0; k<3; ++k){
        int f = tid + k*NTHR; int r = f/24, c = f - r*24;
        *reinterpret_cast<float4*>(&xs[0][r*XSTRIDE + c*4]) = stg[k];
    }
    __syncthreads();

    v2f   hp[5];     // h pairs: hp[k] = (h[2k+hf], h[2k+1-hf]) — replicated in 8-group
    float cst[5];    // c for my parity's u's (replicated within quad)
    #pragma unroll
    for (int k=0; k<5; ++k){ v2f z = {0.f,0.f}; hp[k] = z; cst[k] = 0.f; }

    for (int ch=0; ch<NCHUNK; ++ch){
        const float* xb = &xs[ch&1][bl*XSTRIDE];
        if (ch+1 < NCHUNK){                          // prefetch next chunk global->regs
            #pragma unroll
            for (int k=0; k<3; ++k){
                int f = tid + k*NTHR; int r = f/24, c = f - r*24;
                stg[k] = *reinterpret_cast<const float4*>(
                    xrow + (size_t)r*(SEQT*NIN) + (ch+1)*(TC*NIN) + c*4);
            }
        }

        v2f xa0 = *reinterpret_cast<const v2f*>(xb + 0);
        v2f xa1 = *reinterpret_cast<const v2f*>(xb + 2);
        v2f xa2 = *reinterpret_cast<const v2f*>(xb + 4);

        #pragma unroll 2
        for (int tt=0; tt<TC; ++tt){
            // prefetch next step's x (wraps to step 0 at chunk end; dead value)
            const float* xn = xb + ((tt+1)&(TC-1))*NIN;
            v2f xn0 = *reinterpret_cast<const v2f*>(xn + 0);
            v2f xn1 = *reinterpret_cast<const v2f*>(xn + 2);
            v2f xn2 = *reinterpret_cast<const v2f*>(xn + 4);

            // 5 gate pre-activations (my typ, my parity) — packed FMA
            float s_[5];
            #pragma unroll
            for (int uu=0; uu<5; ++uu){
                v2f acc = biasv[uu];
                acc = pk_fma(xa0, wih[uu][0], acc);
                acc = pk_fma(xa1, wih[uu][1], acc);
                acc = pk_fma(xa2, wih[uu][2], acc);
                acc = pk_fma(hp[0], whh[uu][0], acc);
                acc = pk_fma(hp[1], whh[uu][1], acc);
                acc = pk_fma(hp[2], whh[uu][2], acc);
                acc = pk_fma(hp[3], whh[uu][3], acc);
                acc = pk_fma(hp[4], whh[uu][4], acc);
                s_[uu] = acc.x + acc.y;
            }
            // branch-free activation
            float act[5];
            #pragma unroll
            for (int uu=0; uu<5; ++uu){
                float e = fast_exp2(s_[uu]*expk);
                act[uu] = fmaf(pm, fast_rcp(1.0f + e), pa);
            }
            // gather activations across quad
            float gi[5], gf[5], gg[5], go[5];
            #pragma unroll
            for (int uu=0; uu<5; ++uu){
                gi[uu] = QB(act[uu], 0);
                gf[uu] = QB(act[uu], 1);
                gg[uu] = QB(act[uu], 2);
                go[uu] = QB(act[uu], 3);
            }
            // c update (replicated across quad)
            float cu[5];
            #pragma unroll
            for (int uu=0; uu<5; ++uu){
                cu[uu] = fmaf(gf[uu], cst[uu], gi[uu]*gg[uu]);
                cst[uu] = cu[uu];
            }
            // tanh split: lane typ owns uu=typ; everyone computes uu=4 (quad-uniform)
            float csel = tb1 ? (tb0 ? cu[3] : cu[2]) : (tb0 ? cu[1] : cu[0]);
            float e0 = fast_exp2(csel * -2.8853900817779268f);
            float t0 = fmaf(2.0f, fast_rcp(1.0f + e0), -1.0f);
            float e1 = fast_exp2(cu[4] * -2.8853900817779268f);
            float t1 = fmaf(2.0f, fast_rcp(1.0f + e1), -1.0f);
            float th[5];
            th[0] = QB(t0, 0);
            th[1] = QB(t0, 1);
            th[2] = QB(t0, 2);
            th[3] = QB(t0, 3);
            th[4] = t1;
            // h, cross-half mirror, repack
            #pragma unroll
            for (int uu=0; uu<5; ++uu){
                float hmy = go[uu]*th[uu];     // h[2uu+hf]
                float hot = HMIR(hmy);         // h[2uu+1-hf]
                v2f hv = {hmy, hot};
                hp[uu] = hv;
            }
            xa0 = xn0; xa1 = xn1; xa2 = xn2;
        }
        if (ch+1 < NCHUNK){
            #pragma unroll
            for (int k=0; k<3; ++k){
                int f = tid + k*NTHR; int r = f/24, c = f - r*24;
                *reinterpret_cast<float4*>(&xs[(ch+1)&1][r*XSTRIDE + c*4]) = stg[k];
            }
        }
        __syncthreads();
    }

    // final FC + sigmoid: lanes l8==0,1 (half 0 -> natural pair order) write the 2 outputs
    if (l8 < 2){
        float a = bfc[l8];
        const float* wf = Wfc + l8*HID;
        #pragma unroll
        for (int k=0; k<5; ++k){
            a = fmaf(hp[k].x, wf[2*k],   a);
            a = fmaf(hp[k].y, wf[2*k+1], a);
        }
        float e = fast_exp2(a * -1.4426950408889634f);
        const int b = blockIdx.x*BPB + bl;
        out[(size_t)b*2 + l8] = fast_rcp(1.0f + e);
    }
}

extern "C" void kernel_launch(void* const* d_in, const int* in_sizes, int n_in,
                              void* d_out, int out_size, void* d_ws, size_t ws_size,
                              hipStream_t stream) {
    const float* x   = (const float*)d_in[0];
    const float* Wih = (const float*)d_in[1];
    const float* Whh = (const float*)d_in[2];
    const float* bih = (const float*)d_in[3];
    const float* bhh = (const float*)d_in[4];
    const float* Wfc = (const float*)d_in[5];
    const float* bfc = (const float*)d_in[6];
    float* out = (float*)d_out;

    dim3 grid(16384 / BPB);   // 512 blocks -> 2 per CU -> 2 waves/SIMD
    dim3 block(NTHR);
    Model_88459146428723_kernel<<<grid, block, 0, stream>>>(x, Wih, Whh, bih, bhh, Wfc, bfc, out);
}

// Round 6
// 187.885 us; speedup vs baseline: 1.6974x; 1.5870x over previous
//
#include <hip/hip_runtime.h>

typedef float f32x4  __attribute__((ext_vector_type(4)));
typedef short bf16x8 __attribute__((ext_vector_type(8)));

#define SEQT 512
#define TC   16
#define NCH  (SEQT/TC)
#define ROWDW 68              // dwords per batch-row per buffer (16 steps * 4 + 4 pad)
#define BUFDW (16*ROWDW)      // 1088 dwords per buffer per wave

__device__ __forceinline__ float fexp2(float v){ float r; asm("v_exp_f32 %0, %1":"=v"(r):"v"(v)); return r; }
__device__ __forceinline__ float frcp (float v){ float r; asm("v_rcp_f32 %0, %1":"=v"(r):"v"(v)); return r; }
__device__ __forceinline__ unsigned pkbf(float a, float b){ unsigned r; asm("v_cvt_pk_bf16_f32 %0, %1, %2":"=v"(r):"v"(a),"v"(b)); return r; }
__device__ __forceinline__ float sigm (float s){ return frcp(1.0f + fexp2(s * -1.4426950408889634f)); }
__device__ __forceinline__ float tanh_(float s){ return fmaf(2.0f, frcp(1.0f + fexp2(s * -2.8853900817779268f)), -1.0f); }

union FragU { unsigned u[4]; bf16x8 v; uint4 q; };

// Unit-to-cell table: cell (lane-group g, tile t) owns one LSTM unit (i,f,g,o rows).
//   g0:{u6,u7,u0}  g1:{u2,u3,u9}  g2:{u1,-,-}  g3:{u4,u5,u8}
// Chosen so h-routing into the next-step B fragment needs only xor16/xor32 shuffles:
//   B (z = [x(6); h(10)] padded to K=32): g0 words = (x0x1,x2x3,x4x5,h0h1),
//   g1 words = (h2h3,h4h5,h6h7,h8h9), g2/g3 = 0.
__device__ __forceinline__ int unit_of(int cg, int t){
    if (t==0) return cg==0 ? 6 : cg==1 ? 2 : cg==2 ? 1 : 4;
    if (t==1) return cg==0 ? 7 : cg==1 ? 3 : cg==2 ? -1 : 5;
    return      cg==0 ? 0 : cg==1 ? 9 : cg==2 ? -1 : 8;
}

__global__ __launch_bounds__(256)
__attribute__((amdgpu_waves_per_eu(1, 1)))
void Model_88459146428723_kernel(const float* __restrict__ x,
                                 const float* __restrict__ Wih,
                                 const float* __restrict__ Whh,
                                 const float* __restrict__ bih,
                                 const float* __restrict__ bhh,
                                 const float* __restrict__ Wfc,
                                 const float* __restrict__ bfc,
                                 float* __restrict__ out)
{
    __shared__ unsigned xbf[4][2*BUFDW];     // per-wave private double-buffered x (bf16-pair packed)
    __shared__ float hfin[4][16][12];        // final h scatter for the FC

    const int tid = threadIdx.x;
    const int wv = tid >> 6, l = tid & 63, m = l & 15, gq = l >> 4;

    // ---- A fragments: permuted+padded W (3 tiles of 16 gate-rows, K=32) ----
    // A-frag layout (16x16x32): lane holds row (l&15), k = 8*(l>>4)+j, j=0..7.
    FragU wf[3];
    #pragma unroll
    for (int t=0; t<3; ++t){
        const int u  = unit_of(m>>2, t);     // row n=16t+m -> cell (m>>2), type (m&3)
        const int gt = m & 3;
        float av[8];
        #pragma unroll
        for (int j=0; j<8; ++j){
            const int k = 8*gq + j;
            float v = 0.0f;
            if (u >= 0){
                const int row = gt*10 + u;
                if (k < 6)       v = Wih[row*6 + k];
                else if (k < 16) v = Whh[row*10 + (k-6)];
            }
            av[j] = v;
        }
        #pragma unroll
        for (int w=0; w<4; ++w) wf[t].u[w] = pkbf(av[2*w], av[2*w+1]);
    }
    // ---- bias as MFMA C-seed: C[row=16t+4*gq+jD][col=batch] ----
    f32x4 bias[3];
    #pragma unroll
    for (int t=0; t<3; ++t){
        const int u = unit_of(gq, t);
        #pragma unroll
        for (int jD=0; jD<4; ++jD)
            bias[t][jD] = (u>=0) ? (bih[jD*10+u] + bhh[jD*10+u]) : 0.0f;
    }

    // ---- x staging: global f32 -> LDS bf16-pair words [m][t][4 dw] ----
    const float* xwb = x + (size_t)(blockIdx.x*64 + wv*16) * (SEQT*6);
    unsigned* myx = &xbf[wv][0];
    float4 stg[6];

    auto load_ch = [&](int ch){
        #pragma unroll
        for (int k=0; k<6; ++k){
            const int f = l + 64*k, mb = f/24, c4 = f%24;
            stg[k] = *reinterpret_cast<const float4*>(xwb + (size_t)mb*(SEQT*6) + ch*(TC*6) + c4*4);
        }
    };
    auto write_buf = [&](int buf){
        unsigned* dst = myx + buf*BUFDW;
        #pragma unroll
        for (int k=0; k<6; ++k){
            const int f = l + 64*k, mb = f/24, c4 = f%24;
            const int P0 = 2*c4, P1 = P0+1;
            dst[mb*ROWDW + (P0/3)*4 + (P0%3)] = pkbf(stg[k].x, stg[k].y);
            dst[mb*ROWDW + (P1/3)*4 + (P1%3)] = pkbf(stg[k].z, stg[k].w);
        }
    };

    load_ch(0); write_buf(0);
    uint4 xw = *reinterpret_cast<const uint4*>(myx + m*ROWDW);   // t=0

    // initial B: x_0, h = 0
    unsigned B0 = (gq==0) ? xw.x : 0u;
    unsigned B1 = (gq==0) ? xw.y : 0u;
    unsigned B2 = (gq==0) ? xw.z : 0u;
    unsigned B3 = 0u;
    float c0=0.f, c1=0.f, c2=0.f;
    float h0=0.f, h1=0.f, h2=0.f;

    #pragma unroll 1
    for (int ch=0; ch<NCH; ++ch){
        const int cur = ch & 1;
        if (ch+1 < NCH) load_ch(ch+1);       // global->regs, written to LDS at tt==14
        #pragma unroll 2
        for (int tt=0; tt<TC; ++tt){
            FragU Bf; Bf.u[0]=B0; Bf.u[1]=B1; Bf.u[2]=B2; Bf.u[3]=B3;
            f32x4 a0 = __builtin_amdgcn_mfma_f32_16x16x32_bf16(wf[0].v, Bf.v, bias[0], 0,0,0);
            f32x4 a1 = __builtin_amdgcn_mfma_f32_16x16x32_bf16(wf[1].v, Bf.v, bias[1], 0,0,0);
            f32x4 a2 = __builtin_amdgcn_mfma_f32_16x16x32_bf16(wf[2].v, Bf.v, bias[2], 0,0,0);
            // per-tile (i,f,g,o) -> c,h ; all lane-local
            { float iv=sigm(a0[0]), fv=sigm(a0[1]), gv=tanh_(a0[2]), ov=sigm(a0[3]);
              c0 = fmaf(fv, c0, iv*gv); h0 = ov * tanh_(c0); }
            { float iv=sigm(a1[0]), fv=sigm(a1[1]), gv=tanh_(a1[2]), ov=sigm(a1[3]);
              c1 = fmaf(fv, c1, iv*gv); h1 = ov * tanh_(c1); }
            { float iv=sigm(a2[0]), fv=sigm(a2[1]), gv=tanh_(a2[2]), ov=sigm(a2[3]);
              c2 = fmaf(fv, c2, iv*gv); h2 = ov * tanh_(c2); }

            if (tt==14 && ch+1<NCH) write_buf(cur^1);   // stage next chunk before its first read

            uint4 xwn;
            if (tt < 15)          xwn = *reinterpret_cast<const uint4*>(myx + cur*BUFDW + m*ROWDW + (tt+1)*4);
            else if (ch+1 < NCH)  xwn = *reinterpret_cast<const uint4*>(myx + (cur^1)*BUFDW + m*ROWDW);
            else                  xwn = make_uint4(0u,0u,0u,0u);

            // h routing: pkA=(h_t0,h_t1) local pairs; xor32/xor16 moves into g0/g1 dest words
            const unsigned pkA = pkbf(h0, h1);
            const unsigned r1 = (unsigned)__shfl_xor((int)pkA, 32);  // g1 <- g3: (h4,h5)
            const float    r2 = __shfl_xor(h2, 32);                  // g1 <- g3: h8
            const float    r3 = __shfl_xor(h0, 32);                  // g0 <- g2: h1
            const unsigned r4 = (unsigned)__shfl_xor((int)pkA, 16);  // g1 <- g0: (h6,h7)
            const unsigned p01 = pkbf(h2, r3);                       // at g0: (h0,h1)
            const unsigned p89 = pkbf(r2, h2);                       // at g1: (h8,h9)
            B0 = (gq==0) ? xwn.x : (gq==1) ? pkA : 0u;
            B1 = (gq==0) ? xwn.y : (gq==1) ? r1  : 0u;
            B2 = (gq==0) ? xwn.z : (gq==1) ? r4  : 0u;
            B3 = (gq==0) ? p01   : (gq==1) ? p89 : 0u;
        }
    }

    // ---- final FC + sigmoid ----
    {
        const int ua = unit_of(gq,0);
        hfin[wv][m][ua] = h0;
        const int ub = unit_of(gq,1); if (ub>=0) hfin[wv][m][ub] = h1;
        const int uc = unit_of(gq,2); if (uc>=0) hfin[wv][m][uc] = h2;
    }
    __syncthreads();
    if (l < 32){
        const int j = l >> 4, mm = l & 15;
        float a = bfc[j];
        #pragma unroll
        for (int u=0; u<10; ++u) a = fmaf(Wfc[j*10+u], hfin[wv][mm][u], a);
        out[(size_t)(blockIdx.x*64 + wv*16 + mm)*2 + j] = sigm(a);
    }
}

extern "C" void kernel_launch(void* const* d_in, const int* in_sizes, int n_in,
                              void* d_out, int out_size, void* d_ws, size_t ws_size,
                              hipStream_t stream) {
    const float* x   = (const float*)d_in[0];
    const float* Wih = (const float*)d_in[1];
    const float* Whh = (const float*)d_in[2];
    const float* bih = (const float*)d_in[3];
    const float* bhh = (const float*)d_in[4];
    const float* Wfc = (const float*)d_in[5];
    const float* bfc = (const float*)d_in[6];
    float* out = (float*)d_out;

    dim3 grid(16384 / 64);    // 256 blocks x 4 waves = 1024 waves -> 1 wave/SIMD, 16 batches/wave
    dim3 block(256);
    Model_88459146428723_kernel<<<grid, block, 0, stream>>>(x, Wih, Whh, bih, bhh, Wfc, bfc, out);
}

// Round 7
// 171.192 us; speedup vs baseline: 1.8629x; 1.0975x over previous
//
#include <hip/hip_runtime.h>

typedef float f32x4  __attribute__((ext_vector_type(4)));
typedef short bf16x8 __attribute__((ext_vector_type(8)));

#define SEQT 512
#define TC   16
#define NCH  (SEQT/TC)
#define ROWDW 68              // dwords per batch-row per buffer (16 steps * 4 + 4 pad)
#define BUFDW (16*ROWDW)

__device__ __forceinline__ float fexp2(float v){ float r; asm("v_exp_f32 %0, %1":"=v"(r):"v"(v)); return r; }
__device__ __forceinline__ float frcp (float v){ float r; asm("v_rcp_f32 %0, %1":"=v"(r):"v"(v)); return r; }
__device__ __forceinline__ unsigned pkbf(float a, float b){ unsigned r; asm("v_cvt_pk_bf16_f32 %0, %1, %2":"=v"(r):"v"(a),"v"(b)); return r; }
__device__ __forceinline__ float sigm (float s){ return frcp(1.0f + fexp2(s * -1.4426950408889634f)); }
__device__ __forceinline__ float tanh_(float s){ return fmaf(2.0f, frcp(1.0f + fexp2(s * -2.8853900817779268f)), -1.0f); }

union FragU { unsigned u[4]; bf16x8 v; uint4 q; };

// Unit-to-cell map (cell = lane-group cg, tile t), chosen with the K-slot
// permutation below so ONE pkbf(ht0,ht1) forms every group's local B-word and
// the only cross-lane h move (h7: g3->g1) is ONE v_permlane32_swap (VALU).
//   g0:{u0,u1,-}  g1:{u4,u5,u6}  g2:{u2,u3,-}  g3:{u9,u8,u7}
__device__ __forceinline__ int unit_of(int cg, int t){
    if (t==0) return cg==0 ? 0 : cg==1 ? 4 : cg==2 ? 2 : 9;
    if (t==1) return cg==0 ? 1 : cg==1 ? 5 : cg==2 ? 3 : 8;
    return      cg==0 ? -1 : cg==1 ? 6 : cg==2 ? -1 : 7;
}
// K-slot -> z-component (z = [x0..x5, h0..h9]); -1 = zero padding.
// g0: k0..7 = x0..x5,h0,h1 ; g1: k8..11 = h4,h5,h6,h7 ;
// g2: k16,17 = h2,h3 ; g3: k24,25 = h9,h8.
__device__ __forceinline__ int zslot(int k){
    if (k < 6)  return k;          // x0..x5
    if (k == 6) return 6;          // h0
    if (k == 7) return 7;          // h1
    if (k == 8) return 10;         // h4
    if (k == 9) return 11;         // h5
    if (k == 10) return 12;        // h6
    if (k == 11) return 13;        // h7
    if (k == 16) return 8;         // h2
    if (k == 17) return 9;         // h3
    if (k == 24) return 15;        // h9
    if (k == 25) return 14;        // h8
    return -1;
}

__global__ __launch_bounds__(256)
__attribute__((amdgpu_waves_per_eu(1, 1)))
void Model_88459146428723_kernel(const float* __restrict__ x,
                                 const float* __restrict__ Wih,
                                 const float* __restrict__ Whh,
                                 const float* __restrict__ bih,
                                 const float* __restrict__ bhh,
                                 const float* __restrict__ Wfc,
                                 const float* __restrict__ bfc,
                                 float* __restrict__ out)
{
    __shared__ unsigned xbf[4][2*BUFDW];     // per-wave private double-buffered x
    __shared__ float hfin[4][16][12];

    const int tid = threadIdx.x;
    const int wv = tid >> 6, l = tid & 63, m = l & 15, gq = l >> 4;

    // ---- A fragments: lane holds A-row (l&15), k = 8*(l>>4)+j ----
    FragU wf[3];
    #pragma unroll
    for (int t=0; t<3; ++t){
        const int u  = unit_of(m>>2, t);
        const int gt = m & 3;
        float av[8];
        #pragma unroll
        for (int j=0; j<8; ++j){
            const int z = zslot(8*gq + j);
            float v = 0.0f;
            if (u >= 0 && z >= 0){
                const int row = gt*10 + u;
                v = (z < 6) ? Wih[row*6 + z] : Whh[row*10 + (z-6)];
            }
            av[j] = v;
        }
        #pragma unroll
        for (int w=0; w<4; ++w) wf[t].u[w] = pkbf(av[2*w], av[2*w+1]);
    }
    // ---- bias as MFMA C-seed ----
    f32x4 bias[3];
    #pragma unroll
    for (int t=0; t<3; ++t){
        const int u = unit_of(gq, t);
        #pragma unroll
        for (int jD=0; jD<4; ++jD)
            bias[t][jD] = (u>=0) ? (bih[jD*10+u] + bhh[jD*10+u]) : 0.0f;
    }

    // ---- x staging: global f32 -> LDS bf16-pair words, 3 dwords/step (+1 gap) ----
    const float* xwb = x + (size_t)(blockIdx.x*64 + wv*16) * (SEQT*6);
    unsigned* myx = &xbf[wv][0];
    float4 stg[6];

    auto load_ch = [&](int ch){
        #pragma unroll
        for (int k=0; k<6; ++k){
            const int f = l + 64*k, mb = f/24, c4 = f%24;
            stg[k] = *reinterpret_cast<const float4*>(xwb + (size_t)mb*(SEQT*6) + ch*(TC*6) + c4*4);
        }
    };
    auto write_buf = [&](int buf){
        unsigned* dst = myx + buf*BUFDW;
        #pragma unroll
        for (int k=0; k<6; ++k){
            const int f = l + 64*k, mb = f/24, c4 = f%24;
            const int P0 = 2*c4, P1 = P0+1;
            dst[mb*ROWDW + (P0/3)*4 + (P0%3)] = pkbf(stg[k].x, stg[k].y);
            dst[mb*ROWDW + (P1/3)*4 + (P1%3)] = pkbf(stg[k].z, stg[k].w);
        }
    };

    load_ch(0); write_buf(0);
    uint4 xw = *reinterpret_cast<const uint4*>(myx + m*ROWDW);

    const bool is_g0 = (gq==0), is_g1 = (gq==1);

    unsigned B0 = is_g0 ? xw.x : 0u;
    unsigned B1 = is_g0 ? xw.y : 0u;
    unsigned B2 = is_g0 ? xw.z : 0u;
    unsigned B3 = 0u;
    float c0=0.f, c1=0.f, c2=0.f;
    float ht0=0.f, ht1=0.f, ht2=0.f;

    #pragma unroll 1
    for (int ch=0; ch<NCH; ++ch){
        const int cur = ch & 1;
        if (ch+1 < NCH) load_ch(ch+1);
        #pragma unroll 2
        for (int tt=0; tt<TC; ++tt){
            FragU Bf; Bf.u[0]=B0; Bf.u[1]=B1; Bf.u[2]=B2; Bf.u[3]=B3;
            f32x4 a0 = __builtin_amdgcn_mfma_f32_16x16x32_bf16(wf[0].v, Bf.v, bias[0], 0,0,0);
            f32x4 a1 = __builtin_amdgcn_mfma_f32_16x16x32_bf16(wf[1].v, Bf.v, bias[1], 0,0,0);
            f32x4 a2 = __builtin_amdgcn_mfma_f32_16x16x32_bf16(wf[2].v, Bf.v, bias[2], 0,0,0);

            { float iv=sigm(a0[0]), fv=sigm(a0[1]), gv=tanh_(a0[2]), ov=sigm(a0[3]);
              c0 = fmaf(fv, c0, iv*gv); ht0 = ov * tanh_(c0); }
            { float iv=sigm(a1[0]), fv=sigm(a1[1]), gv=tanh_(a1[2]), ov=sigm(a1[3]);
              c1 = fmaf(fv, c1, iv*gv); ht1 = ov * tanh_(c1); }
            { float iv=sigm(a2[0]), fv=sigm(a2[1]), gv=tanh_(a2[2]), ov=sigm(a2[3]);
              c2 = fmaf(fv, c2, iv*gv); ht2 = ov * tanh_(c2); }

            if (tt==14 && ch+1<NCH) write_buf(cur^1);

            uint4 xwn;
            if (tt < 15)          xwn = *reinterpret_cast<const uint4*>(myx + cur*BUFDW + m*ROWDW + (tt+1)*4);
            else if (ch+1 < NCH)  xwn = *reinterpret_cast<const uint4*>(myx + (cur^1)*BUFDW + m*ROWDW);
            else                  xwn = make_uint4(0u,0u,0u,0u);

            // routing: pkA is every group's local word; one permlane32_swap
            // moves g3's ht2 (=h7) to g1 for the (h6,h7) word. No LDS ops.
            const unsigned pkA = pkbf(ht0, ht1);
            unsigned sa = __float_as_uint(ht2), sb = sa;
            asm("v_permlane32_swap_b32 %0, %1" : "+v"(sa), "+v"(sb));
            // lanes <32 see partner's value in sb (g1 <- g3: h7)
            const unsigned pkB = pkbf(ht2, __uint_as_float(sb));

            B0 = is_g0 ? xwn.x : pkA;
            B1 = is_g0 ? xwn.y : (is_g1 ? pkB : 0u);
            B2 = is_g0 ? xwn.z : 0u;
            B3 = is_g0 ? pkA   : 0u;
        }
    }

    // ---- final FC + sigmoid ----
    {
        const int ua = unit_of(gq,0);            hfin[wv][m][ua] = ht0;
        const int ub = unit_of(gq,1);            hfin[wv][m][ub] = ht1;
        const int uc = unit_of(gq,2); if (uc>=0) hfin[wv][m][uc] = ht2;
    }
    __syncthreads();
    if (l < 32){
        const int j = l >> 4, mm = l & 15;
        float a = bfc[j];
        #pragma unroll
        for (int u=0; u<10; ++u) a = fmaf(Wfc[j*10+u], hfin[wv][mm][u], a);
        out[(size_t)(blockIdx.x*64 + wv*16 + mm)*2 + j] = sigm(a);
    }
}

extern "C" void kernel_launch(void* const* d_in, const int* in_sizes, int n_in,
                              void* d_out, int out_size, void* d_ws, size_t ws_size,
                              hipStream_t stream) {
    const float* x   = (const float*)d_in[0];
    const float* Wih = (const float*)d_in[1];
    const float* Whh = (const float*)d_in[2];
    const float* bih = (const float*)d_in[3];
    const float* bhh = (const float*)d_in[4];
    const float* Wfc = (const float*)d_in[5];
    const float* bfc = (const float*)d_in[6];
    float* out = (float*)d_out;

    dim3 grid(16384 / 64);    // 256 blocks x 4 waves = 1024 waves -> 1/SIMD, 16 batches/wave
    dim3 block(256);
    Model_88459146428723_kernel<<<grid, block, 0, stream>>>(x, Wih, Whh, bih, bhh, Wfc, bfc, out);
}

// Round 8
// 156.885 us; speedup vs baseline: 2.0328x; 1.0912x over previous
//
#include <hip/hip_runtime.h>

typedef float f32x4  __attribute__((ext_vector_type(4)));
typedef short bf16x8 __attribute__((ext_vector_type(8)));

#define SEQT 512
#define TC   16
#define NCH  (SEQT/TC)
#define ROWDW 68              // dwords per batch-row per buffer (16 steps * 4 + 4 pad)
#define BUFDW (16*ROWDW)

__device__ __forceinline__ float fexp2(float v){ float r; asm("v_exp_f32 %0, %1":"=v"(r):"v"(v)); return r; }
__device__ __forceinline__ float frcp (float v){ float r; asm("v_rcp_f32 %0, %1":"=v"(r):"v"(v)); return r; }
__device__ __forceinline__ unsigned pkbf(float a, float b){ unsigned r; asm("v_cvt_pk_bf16_f32 %0, %1, %2":"=v"(r):"v"(a),"v"(b)); return r; }
__device__ __forceinline__ float sigm (float s){ return frcp(1.0f + fexp2(s * -1.4426950408889634f)); }

union FragU { unsigned u[4]; bf16x8 v; uint4 q; };

// Unit-to-cell map (cell = lane-group cg, tile t), chosen with the K-slot
// permutation below so ONE pkbf(ht0,ht1) forms every group's local B-word and
// the only cross-lane h move (h7: g3->g1) is ONE v_permlane32_swap (VALU).
//   g0:{u0,u1,-}  g1:{u4,u5,u6}  g2:{u2,u3,-}  g3:{u9,u8,u7}
__device__ __forceinline__ int unit_of(int cg, int t){
    if (t==0) return cg==0 ? 0 : cg==1 ? 4 : cg==2 ? 2 : 9;
    if (t==1) return cg==0 ? 1 : cg==1 ? 5 : cg==2 ? 3 : 8;
    return      cg==0 ? -1 : cg==1 ? 6 : cg==2 ? -1 : 7;
}
// K-slot -> z-component (z = [x0..x5, h0..h9]); -1 = zero padding.
__device__ __forceinline__ int zslot(int k){
    if (k < 6)  return k;
    if (k == 6) return 6;
    if (k == 7) return 7;
    if (k == 8) return 10;
    if (k == 9) return 11;
    if (k == 10) return 12;
    if (k == 11) return 13;
    if (k == 16) return 8;
    if (k == 17) return 9;
    if (k == 24) return 15;
    if (k == 25) return 14;
    return -1;
}

// LSTM cell with combined reciprocals:
//   i*g = (1-Eg)/[(1+Ei)(1+Eg)],  h = o*tanh(c) = (1-Ec)/[(1+Eo)(1+Ec)]
// 5 exp + 3 rcp per unit (vs 5+5 naive).
__device__ __forceinline__ void cell(const f32x4 a, float& c, float& h){
    const float K1 = -1.4426950408889634f;   // -log2(e)
    const float K2 = -2.8853900817779268f;   // -2*log2(e)
    float Ei = fexp2(a[0]*K1);
    float Ef = fexp2(a[1]*K1);
    float Eg = fexp2(a[2]*K2);
    float Eo = fexp2(a[3]*K1);
    float rig = frcp((1.0f+Ei)*(1.0f+Eg));
    float ig  = (1.0f-Eg)*rig;
    float sf  = frcp(1.0f+Ef);
    c = fmaf(sf, c, ig);
    float Ec  = fexp2(c*K2);
    float roc = frcp((1.0f+Eo)*(1.0f+Ec));
    h = (1.0f-Ec)*roc;
}

__global__ __launch_bounds__(256)
__attribute__((amdgpu_waves_per_eu(1, 1)))
void Model_88459146428723_kernel(const float* __restrict__ x,
                                 const float* __restrict__ Wih,
                                 const float* __restrict__ Whh,
                                 const float* __restrict__ bih,
                                 const float* __restrict__ bhh,
                                 const float* __restrict__ Wfc,
                                 const float* __restrict__ bfc,
                                 float* __restrict__ out)
{
    __shared__ unsigned xbf[4][2*BUFDW];     // per-wave private double-buffered x
    __shared__ float hfin[4][16][12];

    const int tid = threadIdx.x;
    const int wv = tid >> 6, l = tid & 63, m = l & 15, gq = l >> 4;

    // ---- A fragments: lane holds A-row (l&15), k = 8*(l>>4)+j ----
    FragU wf[3];
    #pragma unroll
    for (int t=0; t<3; ++t){
        const int u  = unit_of(m>>2, t);
        const int gt = m & 3;
        float av[8];
        #pragma unroll
        for (int j=0; j<8; ++j){
            const int z = zslot(8*gq + j);
            float v = 0.0f;
            if (u >= 0 && z >= 0){
                const int row = gt*10 + u;
                v = (z < 6) ? Wih[row*6 + z] : Whh[row*10 + (z-6)];
            }
            av[j] = v;
        }
        #pragma unroll
        for (int w=0; w<4; ++w) wf[t].u[w] = pkbf(av[2*w], av[2*w+1]);
    }
    // ---- bias as MFMA C-seed ----
    f32x4 bias[3];
    #pragma unroll
    for (int t=0; t<3; ++t){
        const int u = unit_of(gq, t);
        #pragma unroll
        for (int jD=0; jD<4; ++jD)
            bias[t][jD] = (u>=0) ? (bih[jD*10+u] + bhh[jD*10+u]) : 0.0f;
    }

    // ---- x staging: global f32 -> LDS bf16-pair words, 4 dwords/step row ----
    const float* xwb = x + (size_t)(blockIdx.x*64 + wv*16) * (SEQT*6);
    unsigned* myx = &xbf[wv][0];
    float4 stg[6];

    auto load_ch = [&](int ch){
        #pragma unroll
        for (int k=0; k<6; ++k){
            const int f = l + 64*k, mb = f/24, c4 = f%24;
            stg[k] = *reinterpret_cast<const float4*>(xwb + (size_t)mb*(SEQT*6) + ch*(TC*6) + c4*4);
        }
    };
    auto write_buf = [&](int buf){
        unsigned* dst = myx + buf*BUFDW;
        #pragma unroll
        for (int k=0; k<6; ++k){
            const int f = l + 64*k, mb = f/24, c4 = f%24;
            const int P0 = 2*c4, P1 = P0+1;
            dst[mb*ROWDW + (P0/3)*4 + (P0%3)] = pkbf(stg[k].x, stg[k].y);
            dst[mb*ROWDW + (P1/3)*4 + (P1%3)] = pkbf(stg[k].z, stg[k].w);
        }
    };

    load_ch(0); write_buf(0);
    uint4 xw = *reinterpret_cast<const uint4*>(myx + m*ROWDW);

    const bool is_g0 = (gq==0), is_g1 = (gq==1);

    unsigned B0 = is_g0 ? xw.x : 0u;
    unsigned B1 = is_g0 ? xw.y : 0u;
    unsigned B2 = is_g0 ? xw.z : 0u;
    unsigned B3 = 0u;
    float c0=0.f, c1=0.f, c2=0.f;
    float ht0=0.f, ht1=0.f, ht2=0.f;

    #pragma unroll 1
    for (int ch=0; ch<NCH; ++ch){
        const int cur = ch & 1;
        if (ch+1 < NCH) load_ch(ch+1);
        const unsigned* abase = myx + cur*BUFDW + m*ROWDW;        // current buffer row
        const unsigned* bbase = myx + (cur^1)*BUFDW + m*ROWDW;    // next buffer row

        #pragma unroll
        for (int tt=0; tt<TC; ++tt){
            FragU Bf; Bf.u[0]=B0; Bf.u[1]=B1; Bf.u[2]=B2; Bf.u[3]=B3;
            f32x4 a0 = __builtin_amdgcn_mfma_f32_16x16x32_bf16(wf[0].v, Bf.v, bias[0], 0,0,0);
            f32x4 a1 = __builtin_amdgcn_mfma_f32_16x16x32_bf16(wf[1].v, Bf.v, bias[1], 0,0,0);
            f32x4 a2 = __builtin_amdgcn_mfma_f32_16x16x32_bf16(wf[2].v, Bf.v, bias[2], 0,0,0);

            cell(a0, c0, ht0);
            cell(a1, c1, ht1);
            cell(a2, c2, ht2);

            if (tt==14 && ch+1<NCH) write_buf(cur^1);   // stage next chunk before its first read

            // next step's x words: static immediate offsets (full unroll)
            uint4 xwn;
            if (tt < 15) xwn = *reinterpret_cast<const uint4*>(abase + (tt+1)*4);
            else         xwn = *reinterpret_cast<const uint4*>(bbase);   // next chunk step 0 (garbage at last chunk: unused)

            // routing: pkA is every group's local word; one permlane32_swap
            // moves g3's ht2 (=h7) to g1 for the (h6,h7) word. No LDS ops.
            const unsigned pkA = pkbf(ht0, ht1);
            unsigned sa = __float_as_uint(ht2), sb = sa;
            asm("v_permlane32_swap_b32 %0, %1" : "+v"(sa), "+v"(sb));
            const unsigned pkB = pkbf(ht2, __uint_as_float(sb));

            B0 = is_g0 ? xwn.x : pkA;
            B1 = is_g0 ? xwn.y : (is_g1 ? pkB : 0u);
            B2 = is_g0 ? xwn.z : 0u;
            B3 = is_g0 ? pkA   : 0u;
        }
    }

    // ---- final FC + sigmoid ----
    {
        const int ua = unit_of(gq,0);            hfin[wv][m][ua] = ht0;
        const int ub = unit_of(gq,1);            hfin[wv][m][ub] = ht1;
        const int uc = unit_of(gq,2); if (uc>=0) hfin[wv][m][uc] = ht2;
    }
    __syncthreads();
    if (l < 32){
        const int j = l >> 4, mm = l & 15;
        float a = bfc[j];
        #pragma unroll
        for (int u=0; u<10; ++u) a = fmaf(Wfc[j*10+u], hfin[wv][mm][u], a);
        out[(size_t)(blockIdx.x*64 + wv*16 + mm)*2 + j] = sigm(a);
    }
}

extern "C" void kernel_launch(void* const* d_in, const int* in_sizes, int n_in,
                              void* d_out, int out_size, void* d_ws, size_t ws_size,
                              hipStream_t stream) {
    const float* x   = (const float*)d_in[0];
    const float* Wih = (const float*)d_in[1];
    const float* Whh = (const float*)d_in[2];
    const float* bih = (const float*)d_in[3];
    const float* bhh = (const float*)d_in[4];
    const float* Wfc = (const float*)d_in[5];
    const float* bfc = (const float*)d_in[6];
    float* out = (float*)d_out;

    dim3 grid(16384 / 64);    // 256 blocks x 4 waves = 1024 waves -> 1/SIMD, 16 batches/wave
    dim3 block(256);
    Model_88459146428723_kernel<<<grid, block, 0, stream>>>(x, Wih, Whh, bih, bhh, Wfc, bfc, out);
}

// Round 9
// 153.767 us; speedup vs baseline: 2.0740x; 1.0203x over previous
//
#include <hip/hip_runtime.h>

typedef float f32x4  __attribute__((ext_vector_type(4)));
typedef short bf16x8 __attribute__((ext_vector_type(8)));

#define SEQT 512
#define TC   16
#define NCH  (SEQT/TC)
#define ROWDW 68              // dwords per batch-row per buffer (16 steps * 4 + 4 pad)
#define BUFDW (16*ROWDW)

// scheduler-visible transcendentals (inline asm hides latency from LLVM and
// blocks software pipelining of the 3 independent cell chains)
#define FEXP2(v) __builtin_amdgcn_exp2f(v)
#define FRCP(v)  __builtin_amdgcn_rcpf(v)
__device__ __forceinline__ unsigned pkbf(float a, float b){ unsigned r; asm("v_cvt_pk_bf16_f32 %0, %1, %2":"=v"(r):"v"(a),"v"(b)); return r; }
__device__ __forceinline__ float sigm (float s){ return FRCP(1.0f + FEXP2(s * -1.4426950408889634f)); }

union FragU { unsigned u[4]; bf16x8 v; uint4 q; };

// Unit-to-cell map (cell = lane-group cg, tile t), chosen with the K-slot
// permutation below so ONE pkbf(ht0,ht1) forms every group's local B-word and
// the only cross-lane h move (h7: g3->g1) is ONE v_permlane32_swap (VALU).
//   g0:{u0,u1,-}  g1:{u4,u5,u6}  g2:{u2,u3,-}  g3:{u9,u8,u7}
__device__ __forceinline__ int unit_of(int cg, int t){
    if (t==0) return cg==0 ? 0 : cg==1 ? 4 : cg==2 ? 2 : 9;
    if (t==1) return cg==0 ? 1 : cg==1 ? 5 : cg==2 ? 3 : 8;
    return      cg==0 ? -1 : cg==1 ? 6 : cg==2 ? -1 : 7;
}
// K-slot -> z-component (z = [x0..x5, h0..h9]); -1 = zero padding.
__device__ __forceinline__ int zslot(int k){
    if (k < 6)  return k;
    if (k == 6) return 6;
    if (k == 7) return 7;
    if (k == 8) return 10;
    if (k == 9) return 11;
    if (k == 10) return 12;
    if (k == 11) return 13;
    if (k == 16) return 8;
    if (k == 17) return 9;
    if (k == 24) return 15;
    if (k == 25) return 14;
    return -1;
}

// LSTM cell, 7 trans (5 exp + 2 rcp):
//   P=(1+Ei)(1+Eg), Q=1+Ef, r=rcp(P*Q):  sigma(f)=P*r,  i*g=(1-Eg)*Q*r
//   h = o*tanh(c) = (1-Ec)/[(1+Eo)(1+Ec)]
__device__ __forceinline__ void cell(const f32x4 a, float& c, float& h){
    const float K1 = -1.4426950408889634f;   // -log2(e)
    const float K2 = -2.8853900817779268f;   // -2*log2(e)
    float Ei = FEXP2(a[0]*K1);
    float Ef = FEXP2(a[1]*K1);
    float Eg = FEXP2(a[2]*K2);
    float Eo = FEXP2(a[3]*K1);
    float P  = (1.0f+Ei)*(1.0f+Eg);
    float Q  = 1.0f+Ef;
    float r  = FRCP(P*Q);
    float ig = (1.0f-Eg)*Q*r;
    float sf = P*r;
    c = fmaf(sf, c, ig);
    float Ec  = FEXP2(c*K2);
    float roc = FRCP((1.0f+Eo)*(1.0f+Ec));
    h = (1.0f-Ec)*roc;
}

__global__ __launch_bounds__(256)
__attribute__((amdgpu_waves_per_eu(1, 1)))
void Model_88459146428723_kernel(const float* __restrict__ x,
                                 const float* __restrict__ Wih,
                                 const float* __restrict__ Whh,
                                 const float* __restrict__ bih,
                                 const float* __restrict__ bhh,
                                 const float* __restrict__ Wfc,
                                 const float* __restrict__ bfc,
                                 float* __restrict__ out)
{
    __shared__ unsigned xbf[4][2*BUFDW];     // per-wave private double-buffered x
    __shared__ float hfin[4][16][12];

    const int tid = threadIdx.x;
    const int wv = tid >> 6, l = tid & 63, m = l & 15, gq = l >> 4;

    // ---- A fragments: lane holds A-row (l&15), k = 8*(l>>4)+j ----
    FragU wf[3];
    #pragma unroll
    for (int t=0; t<3; ++t){
        const int u  = unit_of(m>>2, t);
        const int gt = m & 3;
        float av[8];
        #pragma unroll
        for (int j=0; j<8; ++j){
            const int z = zslot(8*gq + j);
            float v = 0.0f;
            if (u >= 0 && z >= 0){
                const int row = gt*10 + u;
                v = (z < 6) ? Wih[row*6 + z] : Whh[row*10 + (z-6)];
            }
            av[j] = v;
        }
        #pragma unroll
        for (int w=0; w<4; ++w) wf[t].u[w] = pkbf(av[2*w], av[2*w+1]);
    }
    // ---- bias as MFMA C-seed ----
    f32x4 bias[3];
    #pragma unroll
    for (int t=0; t<3; ++t){
        const int u = unit_of(gq, t);
        #pragma unroll
        for (int jD=0; jD<4; ++jD)
            bias[t][jD] = (u>=0) ? (bih[jD*10+u] + bhh[jD*10+u]) : 0.0f;
    }

    // ---- x staging: global f32 -> LDS bf16-pair words, 4 dwords/step row ----
    const float* xwb = x + (size_t)(blockIdx.x*64 + wv*16) * (SEQT*6);
    unsigned* myx = &xbf[wv][0];
    float4 stg[6];

    auto load_ch = [&](int ch){
        #pragma unroll
        for (int k=0; k<6; ++k){
            const int f = l + 64*k, mb = f/24, c4 = f%24;
            stg[k] = *reinterpret_cast<const float4*>(xwb + (size_t)mb*(SEQT*6) + ch*(TC*6) + c4*4);
        }
    };
    auto write_buf = [&](int buf){
        unsigned* dst = myx + buf*BUFDW;
        #pragma unroll
        for (int k=0; k<6; ++k){
            const int f = l + 64*k, mb = f/24, c4 = f%24;
            const int P0 = 2*c4, P1 = P0+1;
            dst[mb*ROWDW + (P0/3)*4 + (P0%3)] = pkbf(stg[k].x, stg[k].y);
            dst[mb*ROWDW + (P1/3)*4 + (P1%3)] = pkbf(stg[k].z, stg[k].w);
        }
    };

    load_ch(0); write_buf(0);
    uint4 xw = *reinterpret_cast<const uint4*>(myx + m*ROWDW);

    const bool is_g0 = (gq==0), is_g1 = (gq==1);

    unsigned B0 = is_g0 ? xw.x : 0u;
    unsigned B1 = is_g0 ? xw.y : 0u;
    unsigned B2 = is_g0 ? xw.z : 0u;
    unsigned B3 = 0u;
    float c0=0.f, c1=0.f, c2=0.f;
    float ht0=0.f, ht1=0.f, ht2=0.f;

    #pragma unroll 1
    for (int ch=0; ch<NCH; ++ch){
        const int cur = ch & 1;
        if (ch+1 < NCH) load_ch(ch+1);
        const unsigned* abase = myx + cur*BUFDW + m*ROWDW;        // current buffer row
        const unsigned* bbase = myx + (cur^1)*BUFDW + m*ROWDW;    // next buffer row

        #pragma unroll
        for (int tt=0; tt<TC; ++tt){
            FragU Bf; Bf.u[0]=B0; Bf.u[1]=B1; Bf.u[2]=B2; Bf.u[3]=B3;
            f32x4 a0 = __builtin_amdgcn_mfma_f32_16x16x32_bf16(wf[0].v, Bf.v, bias[0], 0,0,0);
            f32x4 a1 = __builtin_amdgcn_mfma_f32_16x16x32_bf16(wf[1].v, Bf.v, bias[1], 0,0,0);
            f32x4 a2 = __builtin_amdgcn_mfma_f32_16x16x32_bf16(wf[2].v, Bf.v, bias[2], 0,0,0);

            // next step's x words early: lgkm wait overlaps the cell chains
            uint4 xwn;
            if (tt < 15) xwn = *reinterpret_cast<const uint4*>(abase + (tt+1)*4);
            else         xwn = *reinterpret_cast<const uint4*>(bbase);   // next chunk step 0 (garbage at last chunk: unused)

            cell(a0, c0, ht0);
            cell(a1, c1, ht1);
            cell(a2, c2, ht2);

            if (tt==14 && ch+1<NCH) write_buf(cur^1);   // stage next chunk before its first read

            // routing: pkA is every group's local word; one permlane32_swap
            // moves g3's ht2 (=h7) to g1 for the (h6,h7) word. No LDS ops.
            const unsigned pkA = pkbf(ht0, ht1);
            unsigned sa = __float_as_uint(ht2), sb = sa;
            asm("v_permlane32_swap_b32 %0, %1" : "+v"(sa), "+v"(sb));
            const unsigned pkB = pkbf(ht2, __uint_as_float(sb));

            B0 = is_g0 ? xwn.x : pkA;
            B1 = is_g0 ? xwn.y : (is_g1 ? pkB : 0u);
            B2 = is_g0 ? xwn.z : 0u;
            B3 = is_g0 ? pkA   : 0u;
        }
    }

    // ---- final FC + sigmoid ----
    {
        const int ua = unit_of(gq,0);            hfin[wv][m][ua] = ht0;
        const int ub = unit_of(gq,1);            hfin[wv][m][ub] = ht1;
        const int uc = unit_of(gq,2); if (uc>=0) hfin[wv][m][uc] = ht2;
    }
    __syncthreads();
    if (l < 32){
        const int j = l >> 4, mm = l & 15;
        float a = bfc[j];
        #pragma unroll
        for (int u=0; u<10; ++u) a = fmaf(Wfc[j*10+u], hfin[wv][mm][u], a);
        out[(size_t)(blockIdx.x*64 + wv*16 + mm)*2 + j] = sigm(a);
    }
}

extern "C" void kernel_launch(void* const* d_in, const int* in_sizes, int n_in,
                              void* d_out, int out_size, void* d_ws, size_t ws_size,
                              hipStream_t stream) {
    const float* x   = (const float*)d_in[0];
    const float* Wih = (const float*)d_in[1];
    const float* Whh = (const float*)d_in[2];
    const float* bih = (const float*)d_in[3];
    const float* bhh = (const float*)d_in[4];
    const float* Wfc = (const float*)d_in[5];
    const float* bfc = (const float*)d_in[6];
    float* out = (float*)d_out;

    dim3 grid(16384 / 64);    // 256 blocks x 4 waves = 1024 waves -> 1/SIMD, 16 batches/wave
    dim3 block(256);
    Model_88459146428723_kernel<<<grid, block, 0, stream>>>(x, Wih, Whh, bih, bhh, Wfc, bfc, out);
}